// Round 1
// baseline (45309.747 us; speedup 1.0000x reference)
//
#include <hip/hip_runtime.h>

// MACE interaction: N=50000 nodes, E=800000 edges, C=64 channels, R=8, H=64
// Layout conventions:
//   node_features: (N, 256)  [0:64]=x0, [64+3c+m]=x1[c][m]
//   xt (ws):       (N, 256)  [t*64+c], t=0 -> x0', t=1..3 -> x1'[:,m=t-1]
//   agg (ws):      (N, 256)  same layout as xt
//   out:           (N, 64, 4) flat = n*256 + d*4 + comp

#define FDIM 256

__device__ __forceinline__ float silu_f(float x) {
    return x / (1.0f + __expf(-x));
}

// ---------------- pre transform: x0 = nf@W0/8 ; x1[:,m] = x1m@W1/8 -------------
__global__ void __launch_bounds__(256) pre_kernel(
    const float* __restrict__ nf, const float* __restrict__ W0,
    const float* __restrict__ W1, float* __restrict__ xt, int nNodes)
{
    const int lane = threadIdx.x & 63;
    const int wave = threadIdx.x >> 6;
    const int waveId = blockIdx.x * 4 + wave;
    const int nWaves = gridDim.x * 4;

    // lane owns output channel d=lane: keep W0[:,d], W1[:,d] in VGPRs
    float w0r[64], w1r[64];
#pragma unroll
    for (int c = 0; c < 64; ++c) {
        w0r[c] = W0[c * 64 + lane];
        w1r[c] = W1[c * 64 + lane];
    }

    for (int n = waveId; n < nNodes; n += nWaves) {
        const float* __restrict__ row = nf + (size_t)n * FDIM;
        float a0 = 0.f, a1 = 0.f, a2 = 0.f, a3 = 0.f;
#pragma unroll
        for (int c = 0; c < 64; ++c) {
            // row[] indices are wave-uniform -> scalar loads
            float x0 = row[c];
            float xm0 = row[64 + 3 * c + 0];
            float xm1 = row[64 + 3 * c + 1];
            float xm2 = row[64 + 3 * c + 2];
            a0 = fmaf(x0, w0r[c], a0);
            a1 = fmaf(xm0, w1r[c], a1);
            a2 = fmaf(xm1, w1r[c], a2);
            a3 = fmaf(xm2, w1r[c], a3);
        }
        float* o = xt + (size_t)n * FDIM;
        o[lane]       = a0 * 0.125f;
        o[64 + lane]  = a1 * 0.125f;
        o[128 + lane] = a2 * 0.125f;
        o[192 + lane] = a3 * 0.125f;
    }
}

// ---------------- edge kernel: MLP + tensor-product message + atomic scatter ----
__global__ void __launch_bounds__(256) edge_kernel(
    const float* __restrict__ xt, const float* __restrict__ sph,
    const float* __restrict__ rb, const int* __restrict__ ei,
    const float* __restrict__ W1, const float* __restrict__ W2,
    const float* __restrict__ W3, float* __restrict__ agg, int E)
{
    const int e = blockIdx.x * 256 + threadIdx.x;
    if (e >= E) return;

    // per-edge loads (coalesced: consecutive lanes = consecutive edges)
    const float4 rq0 = *reinterpret_cast<const float4*>(rb + (size_t)e * 8);
    const float4 rq1 = *reinterpret_cast<const float4*>(rb + (size_t)e * 8 + 4);
    const float rbv[8] = {rq0.x, rq0.y, rq0.z, rq0.w, rq1.x, rq1.y, rq1.z, rq1.w};
    const float4 sh = *reinterpret_cast<const float4*>(sph + (size_t)e * 4);
    const float sh1a[3] = {sh.y, sh.z, sh.w};
    const int recv = ei[e];
    const int send = ei[E + e];

    // layer 1: h1 = silu(rb @ W1)   (W1 indices wave-uniform -> s_load)
    float h1[64];
#pragma unroll
    for (int k = 0; k < 64; ++k) {
        float acc = 0.f;
#pragma unroll
        for (int r = 0; r < 8; ++r) acc = fmaf(rbv[r], W1[r * 64 + k], acc);
        h1[k] = silu_f(acc);
    }

    // layer 2: h2 = silu(h1 @ W2)
    float h2[64];
#pragma unroll
    for (int j = 0; j < 64; ++j) {
        float acc = 0.f;
#pragma unroll
        for (int k = 0; k < 64; ++k) acc = fmaf(h1[k], W2[k * 64 + j], acc);
        h2[j] = silu_f(acc);
    }

    const float* __restrict__ xrow = xt + (size_t)send * FDIM;
    float* __restrict__ arow = agg + (size_t)recv * FDIM;

    const float INV_SQRT2 = 0.7071067811865476f;
    const float INV_SQRT3 = 0.5773502691896258f;

    // layer 3 + messages, in channel blocks of 16 (cb loop NOT unrolled:
    // keeps code size down; all array indices inside stay compile-time).
    for (int cb = 0; cb < 4; ++cb) {
        float wv[4][16];
#pragma unroll
        for (int t = 0; t < 4; ++t) {
#pragma unroll
            for (int ci = 0; ci < 16; ++ci) {
                float acc = 0.f;
#pragma unroll
                for (int k = 0; k < 64; ++k)
                    acc = fmaf(h2[k], W3[k * 256 + t * 64 + cb * 16 + ci], acc);
                wv[t][ci] = acc;
            }
        }

        // gather xj for this channel block
        float xj0[16], xj1m[3][16];
#pragma unroll
        for (int q = 0; q < 4; ++q) {
            float4 v0 = *reinterpret_cast<const float4*>(xrow + cb * 16 + 4 * q);
            xj0[4 * q + 0] = v0.x; xj0[4 * q + 1] = v0.y;
            xj0[4 * q + 2] = v0.z; xj0[4 * q + 3] = v0.w;
#pragma unroll
            for (int m = 0; m < 3; ++m) {
                float4 v1 = *reinterpret_cast<const float4*>(
                    xrow + (m + 1) * 64 + cb * 16 + 4 * q);
                xj1m[m][4 * q + 0] = v1.x; xj1m[m][4 * q + 1] = v1.y;
                xj1m[m][4 * q + 2] = v1.z; xj1m[m][4 * q + 3] = v1.w;
            }
        }

        // messages + atomic scatter
#pragma unroll
        for (int ci = 0; ci < 16; ++ci) {
            float x0v = xj0[ci];
            float dotv = (xj1m[0][ci] * sh1a[0] + xj1m[1][ci] * sh1a[1] +
                          xj1m[2][ci] * sh1a[2]) * INV_SQRT3;
            float m0 = (wv[0][ci] * x0v * sh.x + wv[1][ci] * dotv) * INV_SQRT2;
            atomicAdd(arow + cb * 16 + ci, m0);
#pragma unroll
            for (int m = 0; m < 3; ++m) {
                float m1 = (wv[2][ci] * x0v * sh1a[m] +
                            wv[3][ci] * xj1m[m][ci] * sh.x) * INV_SQRT2;
                atomicAdd(arow + (m + 1) * 64 + cb * 16 + ci, m1);
            }
        }
    }
}

// ---------------- post transform: y0 = agg0@W0/8 ; y1[:,m] = agg1m@W1/8 --------
__global__ void __launch_bounds__(256) post_kernel(
    const float* __restrict__ agg, const float* __restrict__ W0,
    const float* __restrict__ W1, float* __restrict__ out, int nNodes)
{
    const int lane = threadIdx.x & 63;
    const int wave = threadIdx.x >> 6;
    const int waveId = blockIdx.x * 4 + wave;
    const int nWaves = gridDim.x * 4;

    float w0r[64], w1r[64];
#pragma unroll
    for (int c = 0; c < 64; ++c) {
        w0r[c] = W0[c * 64 + lane];
        w1r[c] = W1[c * 64 + lane];
    }

    for (int n = waveId; n < nNodes; n += nWaves) {
        const float* __restrict__ row = agg + (size_t)n * FDIM;
        float a0 = 0.f, a1 = 0.f, a2 = 0.f, a3 = 0.f;
#pragma unroll
        for (int c = 0; c < 64; ++c) {
            a0 = fmaf(row[c],       w0r[c], a0);
            a1 = fmaf(row[64 + c],  w1r[c], a1);
            a2 = fmaf(row[128 + c], w1r[c], a2);
            a3 = fmaf(row[192 + c], w1r[c], a3);
        }
        float4 o4;
        o4.x = a0 * 0.125f;
        o4.y = a1 * 0.125f;
        o4.z = a2 * 0.125f;
        o4.w = a3 * 0.125f;
        *reinterpret_cast<float4*>(out + (size_t)n * FDIM + lane * 4) = o4;
    }
}

extern "C" void kernel_launch(void* const* d_in, const int* in_sizes, int n_in,
                              void* d_out, int out_size, void* d_ws, size_t ws_size,
                              hipStream_t stream) {
    const float* nf     = (const float*)d_in[0];
    const float* sph    = (const float*)d_in[1];
    const float* rb     = (const float*)d_in[2];
    const float* preW0  = (const float*)d_in[3];
    const float* preW1  = (const float*)d_in[4];
    const float* mlpW1  = (const float*)d_in[5];
    const float* mlpW2  = (const float*)d_in[6];
    const float* mlpW3  = (const float*)d_in[7];
    const float* postW0 = (const float*)d_in[8];
    const float* postW1 = (const float*)d_in[9];
    const int*   ei     = (const int*)d_in[10];

    const int N = in_sizes[0] / FDIM;   // 50000
    const int E = in_sizes[1] / 4;      // 800000

    float* xt  = (float*)d_ws;                    // N*256 floats
    float* agg = xt + (size_t)N * FDIM;           // N*256 floats

    hipMemsetAsync(agg, 0, (size_t)N * FDIM * sizeof(float), stream);

    pre_kernel<<<2048, 256, 0, stream>>>(nf, preW0, preW1, xt, N);
    edge_kernel<<<(E + 255) / 256, 256, 0, stream>>>(
        xt, sph, rb, ei, mlpW1, mlpW2, mlpW3, agg, E);
    post_kernel<<<2048, 256, 0, stream>>>(agg, postW0, postW1, (float*)d_out, N);
}

// Round 3
// 10477.047 us; speedup vs baseline: 4.3247x; 4.3247x over previous
//
#include <hip/hip_runtime.h>

// MACE interaction: N=50000 nodes, E=800000 edges, C=64, R=8, H=64
// ws layout (floats) — total ~102.4 MB + 21 KB (R1's footprint, known-safe):
//   xt    : N*256   x' after pre-transform, [n*256 + t*64 + c], t=0:x0', t=1..3:x1'[:,m]
//   agg   : N*256   scatter target, same layout
//   W1t   : 512     W1t[k*8+r]  = W1[r*64+k]
//   W2t   : 4096    W2t[j*64+k] = W2[k*64+j]
//   W3t   : 16384   W3t[o*64+k] = W3[k*256+o]

#define FDIM 256

__device__ __forceinline__ float silu_f(float x) {
    return x / (1.0f + __expf(-x));
}

// ---------------- weight transposes (trivial) --------------------------------
__global__ void __launch_bounds__(256) transpose_w(
    const float* __restrict__ W1, const float* __restrict__ W2,
    const float* __restrict__ W3, float* __restrict__ W1t,
    float* __restrict__ W2t, float* __restrict__ W3t)
{
    int i = blockIdx.x * 256 + threadIdx.x;
    if (i < 512)   { int r = i >> 6, k = i & 63;  W1t[k * 8 + r]  = W1[i]; }
    if (i < 4096)  { int k = i >> 6, j = i & 63;  W2t[j * 64 + k] = W2[i]; }
    if (i < 16384) { int k = i >> 8, o = i & 255; W3t[o * 64 + k] = W3[i]; }
}

// ---------------- pre transform: x0 = nf@W0/8 ; x1[:,m] = x1m@W1/8 -----------
__global__ void __launch_bounds__(256) pre_kernel(
    const float* __restrict__ nf, const float* __restrict__ W0,
    const float* __restrict__ W1, float* __restrict__ xt, int nNodes)
{
    const int lane = threadIdx.x & 63;
    const int wave = threadIdx.x >> 6;
    const int waveId = blockIdx.x * 4 + wave;
    const int nWaves = gridDim.x * 4;

    float w0r[64], w1r[64];
#pragma unroll
    for (int c = 0; c < 64; ++c) {
        w0r[c] = W0[c * 64 + lane];
        w1r[c] = W1[c * 64 + lane];
    }

    for (int n = waveId; n < nNodes; n += nWaves) {
        const float* __restrict__ row = nf + (size_t)n * FDIM;
        float a0 = 0.f, a1 = 0.f, a2 = 0.f, a3 = 0.f;
#pragma unroll
        for (int c = 0; c < 64; ++c) {
            float x0  = row[c];
            float xm0 = row[64 + 3 * c + 0];
            float xm1 = row[64 + 3 * c + 1];
            float xm2 = row[64 + 3 * c + 2];
            a0 = fmaf(x0,  w0r[c], a0);
            a1 = fmaf(xm0, w1r[c], a1);
            a2 = fmaf(xm1, w1r[c], a2);
            a3 = fmaf(xm2, w1r[c], a3);
        }
        float* o = xt + (size_t)n * FDIM;
        o[lane]       = a0 * 0.125f;
        o[64 + lane]  = a1 * 0.125f;
        o[128 + lane] = a2 * 0.125f;
        o[192 + lane] = a3 * 0.125f;
    }
}

// ---------------- fused edge kernel: MLP(1,2,3) + message + atomic scatter ---
// lane-per-edge. Register discipline: h1[64] dies after layer 2; layer 3
// chunked at 8 channels (wv[4][8]+xj[4][8] = 64 regs live) -> no spill.
__global__ void __launch_bounds__(256) edge_kernel(
    const float* __restrict__ xt, const float* __restrict__ sph,
    const float* __restrict__ rb, const int* __restrict__ ei,
    const float* __restrict__ W1t, const float* __restrict__ W2t,
    const float* __restrict__ W3t, float* __restrict__ agg, int E)
{
    const int e = blockIdx.x * 256 + threadIdx.x;
    if (e >= E) return;

    // layer 1: h1 = silu(rb @ W1)
    const float4 rq0 = *reinterpret_cast<const float4*>(rb + (size_t)e * 8);
    const float4 rq1 = *reinterpret_cast<const float4*>(rb + (size_t)e * 8 + 4);
    const float rbv[8] = {rq0.x, rq0.y, rq0.z, rq0.w, rq1.x, rq1.y, rq1.z, rq1.w};

    float h1[64];
#pragma unroll
    for (int k = 0; k < 64; ++k) {
        float acc = 0.f;
#pragma unroll
        for (int r = 0; r < 8; ++r) acc = fmaf(rbv[r], W1t[k * 8 + r], acc);
        h1[k] = silu_f(acc);
    }

    // layer 2: h2 = silu(h1 @ W2)   (h1 dead afterwards)
    float h2[64];
#pragma unroll
    for (int j = 0; j < 64; ++j) {
        const float* __restrict__ col = W2t + j * 64;  // wave-uniform -> s_load
        float acc = 0.f;
#pragma unroll
        for (int k = 0; k < 64; ++k) acc = fmaf(h1[k], col[k], acc);
        h2[j] = silu_f(acc);
    }

    const float4 sh = *reinterpret_cast<const float4*>(sph + (size_t)e * 4);
    const float sh1a[3] = {sh.y, sh.z, sh.w};
    const int recv = ei[e];
    const int send = ei[E + e];
    const float* __restrict__ xrow = xt + (size_t)send * FDIM;
    float* __restrict__ arow = agg + (size_t)recv * FDIM;

    const float INV_SQRT2 = 0.7071067811865476f;
    const float INV_SQRT3 = 0.5773502691896258f;

    // layer 3 + messages in chunks of 8 channels (cb loop NOT unrolled)
    for (int cb = 0; cb < 8; ++cb) {
        float wv[4][8];
#pragma unroll
        for (int t = 0; t < 4; ++t) {
#pragma unroll
            for (int ci = 0; ci < 8; ++ci) {
                const float* __restrict__ col =
                    W3t + (size_t)(t * 64 + cb * 8 + ci) * 64;  // uniform -> s_load
                float acc = 0.f;
#pragma unroll
                for (int k = 0; k < 64; ++k) acc = fmaf(h2[k], col[k], acc);
                wv[t][ci] = acc;
            }
        }

        float xj0[8], xj1m[3][8];
#pragma unroll
        for (int q = 0; q < 2; ++q) {
            float4 v0 = *reinterpret_cast<const float4*>(xrow + cb * 8 + 4 * q);
            xj0[4 * q + 0] = v0.x; xj0[4 * q + 1] = v0.y;
            xj0[4 * q + 2] = v0.z; xj0[4 * q + 3] = v0.w;
#pragma unroll
            for (int m = 0; m < 3; ++m) {
                float4 v1 = *reinterpret_cast<const float4*>(
                    xrow + (m + 1) * 64 + cb * 8 + 4 * q);
                xj1m[m][4 * q + 0] = v1.x; xj1m[m][4 * q + 1] = v1.y;
                xj1m[m][4 * q + 2] = v1.z; xj1m[m][4 * q + 3] = v1.w;
            }
        }

#pragma unroll
        for (int ci = 0; ci < 8; ++ci) {
            float x0v = xj0[ci];
            float dotv = (xj1m[0][ci] * sh1a[0] + xj1m[1][ci] * sh1a[1] +
                          xj1m[2][ci] * sh1a[2]) * INV_SQRT3;
            float m0 = (wv[0][ci] * x0v * sh.x + wv[1][ci] * dotv) * INV_SQRT2;
            atomicAdd(arow + cb * 8 + ci, m0);
#pragma unroll
            for (int m = 0; m < 3; ++m) {
                float m1 = (wv[2][ci] * x0v * sh1a[m] +
                            wv[3][ci] * xj1m[m][ci] * sh.x) * INV_SQRT2;
                atomicAdd(arow + (m + 1) * 64 + cb * 8 + ci, m1);
            }
        }
    }
}

// ---------------- post transform ---------------------------------------------
__global__ void __launch_bounds__(256) post_kernel(
    const float* __restrict__ agg, const float* __restrict__ W0,
    const float* __restrict__ W1, float* __restrict__ out, int nNodes)
{
    const int lane = threadIdx.x & 63;
    const int wave = threadIdx.x >> 6;
    const int waveId = blockIdx.x * 4 + wave;
    const int nWaves = gridDim.x * 4;

    float w0r[64], w1r[64];
#pragma unroll
    for (int c = 0; c < 64; ++c) {
        w0r[c] = W0[c * 64 + lane];
        w1r[c] = W1[c * 64 + lane];
    }

    for (int n = waveId; n < nNodes; n += nWaves) {
        const float* __restrict__ row = agg + (size_t)n * FDIM;
        float a0 = 0.f, a1 = 0.f, a2 = 0.f, a3 = 0.f;
#pragma unroll
        for (int c = 0; c < 64; ++c) {
            a0 = fmaf(row[c],       w0r[c], a0);
            a1 = fmaf(row[64 + c],  w1r[c], a1);
            a2 = fmaf(row[128 + c], w1r[c], a2);
            a3 = fmaf(row[192 + c], w1r[c], a3);
        }
        float4 o4;
        o4.x = a0 * 0.125f;
        o4.y = a1 * 0.125f;
        o4.z = a2 * 0.125f;
        o4.w = a3 * 0.125f;
        *reinterpret_cast<float4*>(out + (size_t)n * FDIM + lane * 4) = o4;
    }
}

extern "C" void kernel_launch(void* const* d_in, const int* in_sizes, int n_in,
                              void* d_out, int out_size, void* d_ws, size_t ws_size,
                              hipStream_t stream) {
    const float* nf     = (const float*)d_in[0];
    const float* sph    = (const float*)d_in[1];
    const float* rb     = (const float*)d_in[2];
    const float* preW0  = (const float*)d_in[3];
    const float* preW1  = (const float*)d_in[4];
    const float* mlpW1  = (const float*)d_in[5];
    const float* mlpW2  = (const float*)d_in[6];
    const float* mlpW3  = (const float*)d_in[7];
    const float* postW0 = (const float*)d_in[8];
    const float* postW1 = (const float*)d_in[9];
    const int*   ei     = (const int*)d_in[10];

    const int N = in_sizes[0] / FDIM;   // 50000
    const int E = in_sizes[1] / 4;      // 800000

    float* xt  = (float*)d_ws;                  // N*256
    float* agg = xt + (size_t)N * FDIM;         // N*256
    float* W1t = agg + (size_t)N * FDIM;        // 512
    float* W2t = W1t + 512;                     // 4096
    float* W3t = W2t + 4096;                    // 16384

    hipMemsetAsync(agg, 0, (size_t)N * FDIM * sizeof(float), stream);

    transpose_w<<<64, 256, 0, stream>>>(mlpW1, mlpW2, mlpW3, W1t, W2t, W3t);
    pre_kernel<<<2048, 256, 0, stream>>>(nf, preW0, preW1, xt, N);
    edge_kernel<<<(E + 255) / 256, 256, 0, stream>>>(
        xt, sph, rb, ei, W1t, W2t, W3t, agg, E);
    post_kernel<<<2048, 256, 0, stream>>>(agg, postW0, postW1, (float*)d_out, N);
}

// Round 4
// 2616.465 us; speedup vs baseline: 17.3172x; 4.0043x over previous
//
#include <hip/hip_runtime.h>

// MACE interaction: N=50000 nodes, E=800000 edges, C=64, R=8, H=64
// ws layout (floats) — ~102.4 MB + 21 KB (known-safe footprint):
//   xt  : N*256   x' after pre-transform, [n*256 + t*64 + c], t=0:x0', t=1..3:x1'[:,m]
//   agg : N*256   scatter target, same layout
//   W1t : 512     W1t[k*8+r]  = W1[r*64+k]
//   W2t : 4096    W2t[j*64+k] = W2[k*64+j]
//   W3t : 16384   W3t[o*64+k] = W3[k*256+o]

#define FDIM 256

__device__ __forceinline__ float silu_f(float x) {
    return x / (1.0f + __expf(-x));
}

// ---------------- weight transposes (trivial) --------------------------------
__global__ void __launch_bounds__(256) transpose_w(
    const float* __restrict__ W1, const float* __restrict__ W2,
    const float* __restrict__ W3, float* __restrict__ W1t,
    float* __restrict__ W2t, float* __restrict__ W3t)
{
    int i = blockIdx.x * 256 + threadIdx.x;
    if (i < 512)   { int r = i >> 6, k = i & 63;  W1t[k * 8 + r]  = W1[i]; }
    if (i < 4096)  { int k = i >> 6, j = i & 63;  W2t[j * 64 + k] = W2[i]; }
    if (i < 16384) { int k = i >> 8, o = i & 255; W3t[o * 64 + k] = W3[i]; }
}

// ---------------- pre transform: x0 = nf@W0/8 ; x1[:,m] = x1m@W1/8 -----------
__global__ void __launch_bounds__(256) pre_kernel(
    const float* __restrict__ nf, const float* __restrict__ W0,
    const float* __restrict__ W1, float* __restrict__ xt, int nNodes)
{
    const int lane = threadIdx.x & 63;
    const int wave = threadIdx.x >> 6;
    const int waveId = blockIdx.x * 4 + wave;
    const int nWaves = gridDim.x * 4;

    float w0r[64], w1r[64];
#pragma unroll
    for (int c = 0; c < 64; ++c) {
        w0r[c] = W0[c * 64 + lane];
        w1r[c] = W1[c * 64 + lane];
    }

    for (int n = waveId; n < nNodes; n += nWaves) {
        const float* __restrict__ row = nf + (size_t)n * FDIM;
        float a0 = 0.f, a1 = 0.f, a2 = 0.f, a3 = 0.f;
#pragma unroll
        for (int c = 0; c < 64; ++c) {
            float x0  = row[c];
            float xm0 = row[64 + 3 * c + 0];
            float xm1 = row[64 + 3 * c + 1];
            float xm2 = row[64 + 3 * c + 2];
            a0 = fmaf(x0,  w0r[c], a0);
            a1 = fmaf(xm0, w1r[c], a1);
            a2 = fmaf(xm1, w1r[c], a2);
            a3 = fmaf(xm2, w1r[c], a3);
        }
        float* o = xt + (size_t)n * FDIM;
        o[lane]       = a0 * 0.125f;
        o[64 + lane]  = a1 * 0.125f;
        o[128 + lane] = a2 * 0.125f;
        o[192 + lane] = a3 * 0.125f;
    }
}

// ---------------- fused edge kernel: MLP + message + COALESCED atomic scatter -
// lane-per-edge compute (uniform s_load weights), then per-chunk LDS transpose
// so each atomic wave-instruction covers 2 edges x 32 consecutive floats
// (8 aligned 32B sectors) instead of 64 scattered rows (64 sectors).
__global__ void __launch_bounds__(256) edge_kernel(
    const float* __restrict__ xt, const float* __restrict__ sph,
    const float* __restrict__ rb, const int* __restrict__ ei,
    const float* __restrict__ W1t, const float* __restrict__ W2t,
    const float* __restrict__ W3t, float* __restrict__ agg, int E)
{
    const int tid  = threadIdx.x;
    const int lane = tid & 63;
    const int wave = tid >> 6;
    const int eBlockBase = blockIdx.x * 256;
    const int e = eBlockBase + tid;
    const bool valid = (e < E);
    const int eSafe = valid ? e : (E - 1);

    // per-wave private LDS: 64 edges x 32 msg floats (+1 pad) + recv cache
    __shared__ float msgL[4][64][33];   // 33.8 KB
    __shared__ int   recvL[4][64];      // 1 KB

    // ---- layer 1: h1 = silu(rb @ W1) ----
    const float4 rq0 = *reinterpret_cast<const float4*>(rb + (size_t)eSafe * 8);
    const float4 rq1 = *reinterpret_cast<const float4*>(rb + (size_t)eSafe * 8 + 4);
    const float rbv[8] = {rq0.x, rq0.y, rq0.z, rq0.w, rq1.x, rq1.y, rq1.z, rq1.w};

    float h1[64];
#pragma unroll
    for (int k = 0; k < 64; ++k) {
        float acc = 0.f;
#pragma unroll
        for (int r = 0; r < 8; ++r) acc = fmaf(rbv[r], W1t[k * 8 + r], acc);
        h1[k] = silu_f(acc);
    }

    // ---- layer 2: h2 = silu(h1 @ W2) ----
    float h2[64];
#pragma unroll
    for (int j = 0; j < 64; ++j) {
        const float* __restrict__ col = W2t + j * 64;  // wave-uniform -> s_load
        float acc = 0.f;
#pragma unroll
        for (int k = 0; k < 64; ++k) acc = fmaf(h1[k], col[k], acc);
        h2[j] = silu_f(acc);
    }

    const float4 sh = *reinterpret_cast<const float4*>(sph + (size_t)eSafe * 4);
    const float sh1a[3] = {sh.y, sh.z, sh.w};
    const int recv = ei[eSafe];
    const int send = ei[E + eSafe];
    const float* __restrict__ xrow = xt + (size_t)send * FDIM;

    recvL[wave][lane] = recv;

    const float INV_SQRT2 = 0.7071067811865476f;
    const float INV_SQRT3 = 0.5773502691896258f;

    // scatter-phase constants (per thread, fixed across chunks)
    const int jj  = lane & 31;   // which of the 32 chunk floats
    const int tt  = jj >> 3;     // component 0..3
    const int ci2 = jj & 7;      // channel within chunk
    const int sub = lane >> 5;   // 0/1: first or second edge of the pair

    for (int cb = 0; cb < 8; ++cb) {
        // ---- layer 3 for this chunk: wv[t][ci] ----
        float wv[4][8];
#pragma unroll
        for (int t = 0; t < 4; ++t) {
#pragma unroll
            for (int ci = 0; ci < 8; ++ci) {
                const float* __restrict__ col =
                    W3t + (size_t)(t * 64 + cb * 8 + ci) * 64;  // uniform -> s_load
                float acc = 0.f;
#pragma unroll
                for (int k = 0; k < 64; ++k) acc = fmaf(h2[k], col[k], acc);
                wv[t][ci] = acc;
            }
        }

        // ---- gather xj chunk ----
        float xj0[8], xj1m[3][8];
#pragma unroll
        for (int q = 0; q < 2; ++q) {
            float4 v0 = *reinterpret_cast<const float4*>(xrow + cb * 8 + 4 * q);
            xj0[4 * q + 0] = v0.x; xj0[4 * q + 1] = v0.y;
            xj0[4 * q + 2] = v0.z; xj0[4 * q + 3] = v0.w;
#pragma unroll
            for (int m = 0; m < 3; ++m) {
                float4 v1 = *reinterpret_cast<const float4*>(
                    xrow + (m + 1) * 64 + cb * 8 + 4 * q);
                xj1m[m][4 * q + 0] = v1.x; xj1m[m][4 * q + 1] = v1.y;
                xj1m[m][4 * q + 2] = v1.z; xj1m[m][4 * q + 3] = v1.w;
            }
        }

        // ---- messages -> LDS (thread writes its own row; 2-way banks, free) --
#pragma unroll
        for (int ci = 0; ci < 8; ++ci) {
            float x0v = xj0[ci];
            float dotv = (xj1m[0][ci] * sh1a[0] + xj1m[1][ci] * sh1a[1] +
                          xj1m[2][ci] * sh1a[2]) * INV_SQRT3;
            msgL[wave][lane][ci] =
                (wv[0][ci] * x0v * sh.x + wv[1][ci] * dotv) * INV_SQRT2;
#pragma unroll
            for (int m = 0; m < 3; ++m) {
                msgL[wave][lane][8 * (m + 1) + ci] =
                    (wv[2][ci] * x0v * sh1a[m] +
                     wv[3][ci] * xj1m[m][ci] * sh.x) * INV_SQRT2;
            }
        }

        __syncthreads();   // uniform control flow; orders LDS write -> read

        // ---- coalesced scatter: lanes cover 2 edges x 32 floats per iter ----
        for (int ep = 0; ep < 32; ++ep) {
            const int eL = 2 * ep + sub;                  // edge slot in wave
            const float v = msgL[wave][eL][jj];
            const int eg = eBlockBase + wave * 64 + eL;   // global edge id
            if (eg < E) {
                const int r = recvL[wave][eL];
                atomicAdd(agg + (size_t)r * FDIM + tt * 64 + cb * 8 + ci2, v);
            }
        }

        __syncthreads();   // protect msgL reuse across chunks (cross-wave safe)
    }
}

// ---------------- post transform ---------------------------------------------
__global__ void __launch_bounds__(256) post_kernel(
    const float* __restrict__ agg, const float* __restrict__ W0,
    const float* __restrict__ W1, float* __restrict__ out, int nNodes)
{
    const int lane = threadIdx.x & 63;
    const int wave = threadIdx.x >> 6;
    const int waveId = blockIdx.x * 4 + wave;
    const int nWaves = gridDim.x * 4;

    float w0r[64], w1r[64];
#pragma unroll
    for (int c = 0; c < 64; ++c) {
        w0r[c] = W0[c * 64 + lane];
        w1r[c] = W1[c * 64 + lane];
    }

    for (int n = waveId; n < nNodes; n += nWaves) {
        const float* __restrict__ row = agg + (size_t)n * FDIM;
        float a0 = 0.f, a1 = 0.f, a2 = 0.f, a3 = 0.f;
#pragma unroll
        for (int c = 0; c < 64; ++c) {
            a0 = fmaf(row[c],       w0r[c], a0);
            a1 = fmaf(row[64 + c],  w1r[c], a1);
            a2 = fmaf(row[128 + c], w1r[c], a2);
            a3 = fmaf(row[192 + c], w1r[c], a3);
        }
        float4 o4;
        o4.x = a0 * 0.125f;
        o4.y = a1 * 0.125f;
        o4.z = a2 * 0.125f;
        o4.w = a3 * 0.125f;
        *reinterpret_cast<float4*>(out + (size_t)n * FDIM + lane * 4) = o4;
    }
}

extern "C" void kernel_launch(void* const* d_in, const int* in_sizes, int n_in,
                              void* d_out, int out_size, void* d_ws, size_t ws_size,
                              hipStream_t stream) {
    const float* nf     = (const float*)d_in[0];
    const float* sph    = (const float*)d_in[1];
    const float* rb     = (const float*)d_in[2];
    const float* preW0  = (const float*)d_in[3];
    const float* preW1  = (const float*)d_in[4];
    const float* mlpW1  = (const float*)d_in[5];
    const float* mlpW2  = (const float*)d_in[6];
    const float* mlpW3  = (const float*)d_in[7];
    const float* postW0 = (const float*)d_in[8];
    const float* postW1 = (const float*)d_in[9];
    const int*   ei     = (const int*)d_in[10];

    const int N = in_sizes[0] / FDIM;   // 50000
    const int E = in_sizes[1] / 4;      // 800000

    float* xt  = (float*)d_ws;                  // N*256
    float* agg = xt + (size_t)N * FDIM;         // N*256
    float* W1t = agg + (size_t)N * FDIM;        // 512
    float* W2t = W1t + 512;                     // 4096
    float* W3t = W2t + 4096;                    // 16384

    hipMemsetAsync(agg, 0, (size_t)N * FDIM * sizeof(float), stream);

    transpose_w<<<64, 256, 0, stream>>>(mlpW1, mlpW2, mlpW3, W1t, W2t, W3t);
    pre_kernel<<<2048, 256, 0, stream>>>(nf, preW0, preW1, xt, N);
    edge_kernel<<<(E + 255) / 256, 256, 0, stream>>>(
        xt, sph, rb, ei, W1t, W2t, W3t, agg, E);
    post_kernel<<<2048, 256, 0, stream>>>(agg, postW0, postW1, (float*)d_out, N);
}

// Round 5
// 2506.920 us; speedup vs baseline: 18.0739x; 1.0437x over previous
//
#include <hip/hip_runtime.h>

// MACE interaction: N=50000 nodes, E=800000 edges, C=64, R=8, H=64
// ws layout (floats) — ~102.4 MB + 21 KB (known-safe footprint):
//   xt  : N*256   x' after pre-transform, [n*256 + t*64 + c], t=0:x0', t=1..3:x1'[:,m]
//   agg : N*256   scatter target, same layout
//   W1t : 512     W1t[k*8+r]  = W1[r*64+k]
//   W2t : 4096    W2t[j*64+k] = W2[k*64+j]
//   W3t : 16384   W3t[o*64+k] = W3[k*256+o]

#define FDIM 256

__device__ __forceinline__ float silu_f(float x) {
    return x / (1.0f + __expf(-x));
}

// ---------------- weight transposes (trivial) --------------------------------
__global__ void __launch_bounds__(256) transpose_w(
    const float* __restrict__ W1, const float* __restrict__ W2,
    const float* __restrict__ W3, float* __restrict__ W1t,
    float* __restrict__ W2t, float* __restrict__ W3t)
{
    int i = blockIdx.x * 256 + threadIdx.x;
    if (i < 512)   { int r = i >> 6, k = i & 63;  W1t[k * 8 + r]  = W1[i]; }
    if (i < 4096)  { int k = i >> 6, j = i & 63;  W2t[j * 64 + k] = W2[i]; }
    if (i < 16384) { int k = i >> 8, o = i & 255; W3t[o * 64 + k] = W3[i]; }
}

// ---------------- pre transform: x0 = nf@W0/8 ; x1[:,m] = x1m@W1/8 -----------
__global__ void __launch_bounds__(256) pre_kernel(
    const float* __restrict__ nf, const float* __restrict__ W0,
    const float* __restrict__ W1, float* __restrict__ xt, int nNodes)
{
    const int lane = threadIdx.x & 63;
    const int wave = threadIdx.x >> 6;
    const int waveId = blockIdx.x * 4 + wave;
    const int nWaves = gridDim.x * 4;

    float w0r[64], w1r[64];
#pragma unroll
    for (int c = 0; c < 64; ++c) {
        w0r[c] = W0[c * 64 + lane];
        w1r[c] = W1[c * 64 + lane];
    }

    for (int n = waveId; n < nNodes; n += nWaves) {
        const float* __restrict__ row = nf + (size_t)n * FDIM;
        float a0 = 0.f, a1 = 0.f, a2 = 0.f, a3 = 0.f;
#pragma unroll
        for (int c = 0; c < 64; ++c) {
            float x0  = row[c];
            float xm0 = row[64 + 3 * c + 0];
            float xm1 = row[64 + 3 * c + 1];
            float xm2 = row[64 + 3 * c + 2];
            a0 = fmaf(x0,  w0r[c], a0);
            a1 = fmaf(xm0, w1r[c], a1);
            a2 = fmaf(xm1, w1r[c], a2);
            a3 = fmaf(xm2, w1r[c], a3);
        }
        float* o = xt + (size_t)n * FDIM;
        o[lane]       = a0 * 0.125f;
        o[64 + lane]  = a1 * 0.125f;
        o[128 + lane] = a2 * 0.125f;
        o[192 + lane] = a3 * 0.125f;
    }
}

// ---------------- fused edge kernel: MLP + message + coalesced atomic scatter -
// lane-per-edge compute (uniform s_load weights). Per-chunk LDS transpose is
// WAVE-PRIVATE: no __syncthreads (which would s_waitcnt vmcnt(0) and drain the
// in-flight atomics every chunk). DS ops from one wave execute in order, so
// write->read ordering needs only lgkmcnt(0); atomics are fire-and-forget and
// retire under the next chunk's 2048-FMA layer-3 block.
__global__ void __launch_bounds__(256) edge_kernel(
    const float* __restrict__ xt, const float* __restrict__ sph,
    const float* __restrict__ rb, const int* __restrict__ ei,
    const float* __restrict__ W1t, const float* __restrict__ W2t,
    const float* __restrict__ W3t, float* __restrict__ agg, int E)
{
    const int tid  = threadIdx.x;
    const int lane = tid & 63;
    const int wave = tid >> 6;
    const int eBlockBase = blockIdx.x * 256;
    const int e = eBlockBase + tid;
    const int eSafe = (e < E) ? e : (E - 1);

    // per-wave private LDS: 64 edges x 32 msg floats (+1 pad) + recv cache
    __shared__ float msgL[4][64][33];   // 33.8 KB
    __shared__ int   recvL[4][64];      // 1 KB

    // ---- layer 1: h1 = silu(rb @ W1) ----
    const float4 rq0 = *reinterpret_cast<const float4*>(rb + (size_t)eSafe * 8);
    const float4 rq1 = *reinterpret_cast<const float4*>(rb + (size_t)eSafe * 8 + 4);
    const float rbv[8] = {rq0.x, rq0.y, rq0.z, rq0.w, rq1.x, rq1.y, rq1.z, rq1.w};

    float h1[64];
#pragma unroll
    for (int k = 0; k < 64; ++k) {
        float acc = 0.f;
#pragma unroll
        for (int r = 0; r < 8; ++r) acc = fmaf(rbv[r], W1t[k * 8 + r], acc);
        h1[k] = silu_f(acc);
    }

    // ---- layer 2: h2 = silu(h1 @ W2) ----
    float h2[64];
#pragma unroll
    for (int j = 0; j < 64; ++j) {
        const float* __restrict__ col = W2t + j * 64;  // wave-uniform -> s_load
        float acc = 0.f;
#pragma unroll
        for (int k = 0; k < 64; ++k) acc = fmaf(h1[k], col[k], acc);
        h2[j] = silu_f(acc);
    }

    const float4 sh = *reinterpret_cast<const float4*>(sph + (size_t)eSafe * 4);
    const float sh1a[3] = {sh.y, sh.z, sh.w};
    const int recv = ei[eSafe];
    const int send = ei[E + eSafe];
    const float* __restrict__ xrow = xt + (size_t)send * FDIM;

    recvL[wave][lane] = recv;

    const float INV_SQRT2 = 0.7071067811865476f;
    const float INV_SQRT3 = 0.5773502691896258f;

    // scatter-phase constants (fixed across chunks)
    const int jj  = lane & 31;   // which of the 32 chunk floats
    const int tt  = jj >> 3;     // component 0..3
    const int ci2 = jj & 7;      // channel within chunk
    const int sub = lane >> 5;   // 0/1: first or second edge of the pair
    float* const aggScat = agg + tt * 64 + ci2;   // + r*FDIM + cb*8 at use

    for (int cb = 0; cb < 8; ++cb) {
        // ---- gather xj chunk FIRST (loads issue early, vmcnt hides under FMAs)
        float xj0[8], xj1m[3][8];
#pragma unroll
        for (int q = 0; q < 2; ++q) {
            float4 v0 = *reinterpret_cast<const float4*>(xrow + cb * 8 + 4 * q);
            xj0[4 * q + 0] = v0.x; xj0[4 * q + 1] = v0.y;
            xj0[4 * q + 2] = v0.z; xj0[4 * q + 3] = v0.w;
#pragma unroll
            for (int m = 0; m < 3; ++m) {
                float4 v1 = *reinterpret_cast<const float4*>(
                    xrow + (m + 1) * 64 + cb * 8 + 4 * q);
                xj1m[m][4 * q + 0] = v1.x; xj1m[m][4 * q + 1] = v1.y;
                xj1m[m][4 * q + 2] = v1.z; xj1m[m][4 * q + 3] = v1.w;
            }
        }

        // ---- layer 3 for this chunk: wv[t][ci] (pure SGPR-stream FMAs) ----
        float wv[4][8];
#pragma unroll
        for (int t = 0; t < 4; ++t) {
#pragma unroll
            for (int ci = 0; ci < 8; ++ci) {
                const float* __restrict__ col =
                    W3t + (size_t)(t * 64 + cb * 8 + ci) * 64;  // uniform -> s_load
                float acc = 0.f;
#pragma unroll
                for (int k = 0; k < 64; ++k) acc = fmaf(h2[k], col[k], acc);
                wv[t][ci] = acc;
            }
        }

        // ---- messages -> wave-private LDS rows ----
#pragma unroll
        for (int ci = 0; ci < 8; ++ci) {
            float x0v = xj0[ci];
            float dotv = (xj1m[0][ci] * sh1a[0] + xj1m[1][ci] * sh1a[1] +
                          xj1m[2][ci] * sh1a[2]) * INV_SQRT3;
            msgL[wave][lane][ci] =
                (wv[0][ci] * x0v * sh.x + wv[1][ci] * dotv) * INV_SQRT2;
#pragma unroll
            for (int m = 0; m < 3; ++m) {
                msgL[wave][lane][8 * (m + 1) + ci] =
                    (wv[2][ci] * x0v * sh1a[m] +
                     wv[3][ci] * xj1m[m][ci] * sh.x) * INV_SQRT2;
            }
        }

        // wave-private write->read ordering (DS pipe is in-order per wave;
        // this only guarantees the data-return hazard). No s_barrier, so
        // in-flight atomics do NOT get drained here.
        asm volatile("s_waitcnt lgkmcnt(0)" ::: "memory");
        __builtin_amdgcn_sched_barrier(0);

        // ---- coalesced scatter: 2 edges x 32 consecutive floats per iter ----
        for (int ep = 0; ep < 32; ++ep) {
            const int eL = 2 * ep + sub;                  // edge slot in wave
            const float v = msgL[wave][eL][jj];
            const int eg = eBlockBase + wave * 64 + eL;   // global edge id
            if (eg < E) {
                const int r = recvL[wave][eL];
                atomicAdd(aggScat + (size_t)r * FDIM + cb * 8, v);
            }
        }
        // next chunk's ds_writes can't pass this chunk's ds_reads (in-order DS,
        // may-alias) -> no extra sync needed before reuse of msgL.
    }
}

// ---------------- post transform ---------------------------------------------
__global__ void __launch_bounds__(256) post_kernel(
    const float* __restrict__ agg, const float* __restrict__ W0,
    const float* __restrict__ W1, float* __restrict__ out, int nNodes)
{
    const int lane = threadIdx.x & 63;
    const int wave = threadIdx.x >> 6;
    const int waveId = blockIdx.x * 4 + wave;
    const int nWaves = gridDim.x * 4;

    float w0r[64], w1r[64];
#pragma unroll
    for (int c = 0; c < 64; ++c) {
        w0r[c] = W0[c * 64 + lane];
        w1r[c] = W1[c * 64 + lane];
    }

    for (int n = waveId; n < nNodes; n += nWaves) {
        const float* __restrict__ row = agg + (size_t)n * FDIM;
        float a0 = 0.f, a1 = 0.f, a2 = 0.f, a3 = 0.f;
#pragma unroll
        for (int c = 0; c < 64; ++c) {
            a0 = fmaf(row[c],       w0r[c], a0);
            a1 = fmaf(row[64 + c],  w1r[c], a1);
            a2 = fmaf(row[128 + c], w1r[c], a2);
            a3 = fmaf(row[192 + c], w1r[c], a3);
        }
        float4 o4;
        o4.x = a0 * 0.125f;
        o4.y = a1 * 0.125f;
        o4.z = a2 * 0.125f;
        o4.w = a3 * 0.125f;
        *reinterpret_cast<float4*>(out + (size_t)n * FDIM + lane * 4) = o4;
    }
}

extern "C" void kernel_launch(void* const* d_in, const int* in_sizes, int n_in,
                              void* d_out, int out_size, void* d_ws, size_t ws_size,
                              hipStream_t stream) {
    const float* nf     = (const float*)d_in[0];
    const float* sph    = (const float*)d_in[1];
    const float* rb     = (const float*)d_in[2];
    const float* preW0  = (const float*)d_in[3];
    const float* preW1  = (const float*)d_in[4];
    const float* mlpW1  = (const float*)d_in[5];
    const float* mlpW2  = (const float*)d_in[6];
    const float* mlpW3  = (const float*)d_in[7];
    const float* postW0 = (const float*)d_in[8];
    const float* postW1 = (const float*)d_in[9];
    const int*   ei     = (const int*)d_in[10];

    const int N = in_sizes[0] / FDIM;   // 50000
    const int E = in_sizes[1] / 4;      // 800000

    float* xt  = (float*)d_ws;                  // N*256
    float* agg = xt + (size_t)N * FDIM;         // N*256
    float* W1t = agg + (size_t)N * FDIM;        // 512
    float* W2t = W1t + 512;                     // 4096
    float* W3t = W2t + 4096;                    // 16384

    hipMemsetAsync(agg, 0, (size_t)N * FDIM * sizeof(float), stream);

    transpose_w<<<64, 256, 0, stream>>>(mlpW1, mlpW2, mlpW3, W1t, W2t, W3t);
    pre_kernel<<<2048, 256, 0, stream>>>(nf, preW0, preW1, xt, N);
    edge_kernel<<<(E + 255) / 256, 256, 0, stream>>>(
        xt, sph, rb, ei, W1t, W2t, W3t, agg, E);
    post_kernel<<<2048, 256, 0, stream>>>(agg, postW0, postW1, (float*)d_out, N);
}